// Round 5
// baseline (207.793 us; speedup 1.0000x reference)
//
#include <hip/hip_runtime.h>
#include <hip/hip_bf16.h>
#include <math.h>

// QuantumBottle, fully fused single kernel, occupancy-tuned.
// out_j = b_j + sum_{m in {1,cos,sin}^4} G_j[m] * prod_w u_w[m_w],
// u_w = (1, cos(theta_w), sin(theta_w)), theta_w = tanh(z_w)*scale.
// Each block redundantly builds the 81x4 coefficient table C in LDS,
// then evaluates the multilinear form for QB_S samples per thread.
// QB_S=2 + __launch_bounds__(256,4): VGPR<=128, 4 blocks/CU, 16 waves/CU.

#define QB_S 2   // samples per thread (contiguous pair)

__global__ void __launch_bounds__(256, 4) qb_fused(
    const float* __restrict__ z, const float* __restrict__ scale,
    const float* __restrict__ qw, const float* __restrict__ W,
    const float* __restrict__ bias, float* __restrict__ out, int Bn)
{
    __shared__ float sTrig[8][6];
    __shared__ float Vr[16][16], Vi[16][16];
    __shared__ __align__(16) float4 sM[256];
    __shared__ __align__(16) float sC[81 * 4];

    const int tid = threadIdx.x;

    // ---- phase A1: trig table (24 threads, 1 sincos each) ----
    if (tid < 24) {
        const int g = tid / 3, which = tid % 3;
        const float phi = qw[g * 3 + 0], th = qw[g * 3 + 1], om = qw[g * 3 + 2];
        const float ang = (which == 0) ? 0.5f * th
                        : (which == 1) ? 0.5f * (phi + om)
                                       : 0.5f * (phi - om);
        sTrig[g][2 * which + 0] = cosf(ang);
        sTrig[g][2 * which + 1] = sinf(ang);
    }
    __syncthreads();

    // ---- phase A2: simulate circuit columns (16 threads) ----
    if (tid < 16) {
        float ar[16], ai[16];
        #pragma unroll
        for (int i = 0; i < 16; ++i) { ar[i] = (i == tid) ? 1.0f : 0.0f; ai[i] = 0.0f; }

        for (int l = 0; l < 2; ++l) {
            for (int w = 0; w < 4; ++w) {
                const int g = l * 4 + w;
                const float ct  = sTrig[g][0], st  = sTrig[g][1];
                const float epr = sTrig[g][2], epi = -sTrig[g][3];
                const float emr = sTrig[g][4], emi = -sTrig[g][5];
                const float u00r =  epr * ct, u00i =  epi * ct;
                const float u01r = -emr * st, u01i =  emi * st;
                const float u10r =  emr * st, u10i =  emi * st;
                const float u11r =  epr * ct, u11i = -epi * ct;
                const int bit = 1 << (3 - w);
                #pragma unroll
                for (int i = 0; i < 16; ++i) {
                    if (i & bit) continue;
                    const int i1 = i | bit;
                    const float x0r = ar[i],  x0i = ai[i];
                    const float x1r = ar[i1], x1i = ai[i1];
                    ar[i]  = u00r * x0r - u00i * x0i + u01r * x1r - u01i * x1i;
                    ai[i]  = u00r * x0i + u00i * x0r + u01r * x1i + u01i * x1r;
                    ar[i1] = u10r * x0r - u10i * x0i + u11r * x1r - u11i * x1i;
                    ai[i1] = u10r * x0i + u10i * x0r + u11r * x1i + u11i * x1r;
                }
            }
            #pragma unroll
            for (int w = 0; w < 4; ++w) {
                const int cb = 1 << (3 - w);
                const int tb = 1 << (3 - ((w + 1) & 3));
                #pragma unroll
                for (int i = 0; i < 16; ++i) {
                    if ((i & cb) && !(i & tb)) {
                        const int i1 = i | tb;
                        float tr = ar[i]; ar[i] = ar[i1]; ar[i1] = tr;
                        float ti = ai[i]; ai[i] = ai[i1]; ai[i1] = ti;
                    }
                }
            }
        }
        #pragma unroll
        for (int i = 0; i < 16; ++i) { Vr[i][tid] = ar[i]; Vi[i][tid] = ai[i]; }
    }
    __syncthreads();

    // ---- phase B: M_w[k,kp] (256 threads) ----
    {
        const int k = tid >> 4, kp = tid & 15;
        float m0 = 0.f, m1 = 0.f, m2 = 0.f, m3 = 0.f;
        #pragma unroll
        for (int i = 0; i < 16; ++i) {
            const float pr = Vr[i][k] * Vr[i][kp] + Vi[i][k] * Vi[i][kp];
            m0 += ((i >> 3) & 1) ? -pr : pr;
            m1 += ((i >> 2) & 1) ? -pr : pr;
            m2 += ((i >> 1) & 1) ? -pr : pr;
            m3 += ( i       & 1) ? -pr : pr;
        }
        sM[tid] = make_float4(m0, m1, m2, m3);
    }
    __syncthreads();

    // ---- phase C: G_j[m] over the 3^4 basis (81 threads) ----
    if (tid < 81) {
        const int mm[4] = { tid / 27, (tid / 9) % 3, (tid / 3) % 3, tid % 3 };
        float h0 = 0.f, h1 = 0.f, h2 = 0.f, h3 = 0.f;
        #pragma unroll
        for (int t16 = 0; t16 < 16; ++t16) {
            int k = 0, kp = 0;
            float sgn = 0.0625f;
            #pragma unroll
            for (int w = 0; w < 4; ++w) {
                const int b = (t16 >> (3 - w)) & 1;
                int kw, kpw;
                if (mm[w] == 2) { kw = b; kpw = 1 - b; }
                else            { kw = b; kpw = b; if (mm[w] == 1 && b) sgn = -sgn; }
                k  |= kw  << (3 - w);
                kp |= kpw << (3 - w);
            }
            const float4 mv = sM[k * 16 + kp];
            h0 += sgn * mv.x; h1 += sgn * mv.y; h2 += sgn * mv.z; h3 += sgn * mv.w;
        }
        #pragma unroll
        for (int j = 0; j < 4; ++j) {
            sC[tid * 4 + j] = W[j * 4 + 0] * h0 + W[j * 4 + 1] * h1 +
                              W[j * 4 + 2] * h2 + W[j * 4 + 3] * h3;
        }
    }
    __syncthreads();

    // ---- phase D: multilinear form, QB_S contiguous samples per thread ----
    const int g  = blockIdx.x * 256 + tid;
    const float sc = scale[0];
    const float b0 = bias[0], b1 = bias[1], b2 = bias[2], b3 = bias[3];

    float e01[QB_S][9], e23[QB_S][9];
    bool valid[QB_S];
    #pragma unroll
    for (int s = 0; s < QB_S; ++s) {
        const int idx = g * QB_S + s;
        valid[s] = (idx < Bn);
        const float4 zv = valid[s] ? reinterpret_cast<const float4*>(z)[idx]
                                   : make_float4(0.f, 0.f, 0.f, 0.f);
        const float zz[4] = { zv.x, zv.y, zv.z, zv.w };
        float c[4], sn[4];
        #pragma unroll
        for (int w = 0; w < 4; ++w) {
            const float x = zz[w];
            const float e = __expf(-2.0f * fabsf(x));
            float t = __fdividef(1.0f - e, 1.0f + e);
            t = copysignf(t, x);
            __sincosf(t * sc, &sn[w], &c[w]);
        }
        e01[s][0] = 1.0f;  e01[s][1] = c[1];          e01[s][2] = sn[1];
        e01[s][3] = c[0];  e01[s][4] = c[0] * c[1];   e01[s][5] = c[0] * sn[1];
        e01[s][6] = sn[0]; e01[s][7] = sn[0] * c[1];  e01[s][8] = sn[0] * sn[1];
        e23[s][0] = 1.0f;  e23[s][1] = c[3];          e23[s][2] = sn[3];
        e23[s][3] = c[2];  e23[s][4] = c[2] * c[3];   e23[s][5] = c[2] * sn[3];
        e23[s][6] = sn[2]; e23[s][7] = sn[2] * c[3];  e23[s][8] = sn[2] * sn[3];
    }

    float acc[QB_S][4];
    #pragma unroll
    for (int s = 0; s < QB_S; ++s) {
        acc[s][0] = b0; acc[s][1] = b1; acc[s][2] = b2; acc[s][3] = b3;
    }

    #pragma unroll
    for (int u = 0; u < 9; ++u) {
        float tj[QB_S][4];
        #pragma unroll
        for (int s = 0; s < QB_S; ++s)
            tj[s][0] = tj[s][1] = tj[s][2] = tj[s][3] = 0.0f;
        #pragma unroll
        for (int v = 0; v < 9; ++v) {
            const float4 cc = reinterpret_cast<const float4*>(sC)[u * 9 + v];
            #pragma unroll
            for (int s = 0; s < QB_S; ++s) {
                const float ev = e23[s][v];
                tj[s][0] = fmaf(cc.x, ev, tj[s][0]);
                tj[s][1] = fmaf(cc.y, ev, tj[s][1]);
                tj[s][2] = fmaf(cc.z, ev, tj[s][2]);
                tj[s][3] = fmaf(cc.w, ev, tj[s][3]);
            }
        }
        #pragma unroll
        for (int s = 0; s < QB_S; ++s) {
            const float eu = e01[s][u];
            acc[s][0] = fmaf(eu, tj[s][0], acc[s][0]);
            acc[s][1] = fmaf(eu, tj[s][1], acc[s][1]);
            acc[s][2] = fmaf(eu, tj[s][2], acc[s][2]);
            acc[s][3] = fmaf(eu, tj[s][3], acc[s][3]);
        }
    }

    #pragma unroll
    for (int s = 0; s < QB_S; ++s) {
        const int idx = g * QB_S + s;
        if (valid[s])
            reinterpret_cast<float4*>(out)[idx] =
                make_float4(acc[s][0], acc[s][1], acc[s][2], acc[s][3]);
    }
}

extern "C" void kernel_launch(void* const* d_in, const int* in_sizes, int n_in,
                              void* d_out, int out_size, void* d_ws, size_t ws_size,
                              hipStream_t stream) {
    const float* z  = (const float*)d_in[0];   // (B,4)
    const float* sc = (const float*)d_in[1];   // scalar
    const float* qw = (const float*)d_in[2];   // (2,4,3)
    const float* W  = (const float*)d_in[3];   // (4,4)
    const float* bb = (const float*)d_in[4];   // (4,)
    float* out = (float*)d_out;

    const int Bn = in_sizes[0] / 4;
    const int threads_total = (Bn + QB_S - 1) / QB_S;
    const int blocks = (threads_total + 255) / 256;

    hipLaunchKernelGGL(qb_fused, dim3(blocks), dim3(256), 0, stream,
                       z, sc, qw, W, bb, out, Bn);
}

// Round 6
// 34.534 us; speedup vs baseline: 6.0170x; 6.0170x over previous
//
#include <hip/hip_runtime.h>
#include <hip/hip_bf16.h>
#include <math.h>

// QuantumBottle, fully fused single kernel.
// out_j = b_j + sum_{m in {1,cos,sin}^4} G_j[m] * prod_w u_w[m_w],
// u_w = (1, cos(theta_w), sin(theta_w)), theta_w = tanh(z_w)*scale.
// Each block redundantly builds the 81x4 coefficient table C in LDS,
// then evaluates the multilinear form for QB_S samples per thread.
// QB_S=2, NO min-wave launch bound (round-5 lesson: forcing waves/EU=4
// made the allocator spill the whole working set -> 336 MB scratch writes).

#define QB_S 2   // samples per thread (contiguous pair)

__global__ void __launch_bounds__(256) qb_fused(
    const float* __restrict__ z, const float* __restrict__ scale,
    const float* __restrict__ qw, const float* __restrict__ W,
    const float* __restrict__ bias, float* __restrict__ out, int Bn)
{
    __shared__ float sTrig[8][6];
    __shared__ float Vr[16][16], Vi[16][16];
    __shared__ __align__(16) float4 sM[256];
    __shared__ __align__(16) float sC[81 * 4];

    const int tid = threadIdx.x;

    // ---- phase A1: trig table (24 threads, 1 sincos each) ----
    if (tid < 24) {
        const int g = tid / 3, which = tid % 3;
        const float phi = qw[g * 3 + 0], th = qw[g * 3 + 1], om = qw[g * 3 + 2];
        const float ang = (which == 0) ? 0.5f * th
                        : (which == 1) ? 0.5f * (phi + om)
                                       : 0.5f * (phi - om);
        sTrig[g][2 * which + 0] = cosf(ang);
        sTrig[g][2 * which + 1] = sinf(ang);
    }
    __syncthreads();

    // ---- phase A2: simulate circuit columns (16 threads) ----
    if (tid < 16) {
        float ar[16], ai[16];
        #pragma unroll
        for (int i = 0; i < 16; ++i) { ar[i] = (i == tid) ? 1.0f : 0.0f; ai[i] = 0.0f; }

        for (int l = 0; l < 2; ++l) {
            for (int w = 0; w < 4; ++w) {
                const int g = l * 4 + w;
                const float ct  = sTrig[g][0], st  = sTrig[g][1];
                const float epr = sTrig[g][2], epi = -sTrig[g][3];
                const float emr = sTrig[g][4], emi = -sTrig[g][5];
                const float u00r =  epr * ct, u00i =  epi * ct;
                const float u01r = -emr * st, u01i =  emi * st;
                const float u10r =  emr * st, u10i =  emi * st;
                const float u11r =  epr * ct, u11i = -epi * ct;
                const int bit = 1 << (3 - w);
                #pragma unroll
                for (int i = 0; i < 16; ++i) {
                    if (i & bit) continue;
                    const int i1 = i | bit;
                    const float x0r = ar[i],  x0i = ai[i];
                    const float x1r = ar[i1], x1i = ai[i1];
                    ar[i]  = u00r * x0r - u00i * x0i + u01r * x1r - u01i * x1i;
                    ai[i]  = u00r * x0i + u00i * x0r + u01r * x1i + u01i * x1r;
                    ar[i1] = u10r * x0r - u10i * x0i + u11r * x1r - u11i * x1i;
                    ai[i1] = u10r * x0i + u10i * x0r + u11r * x1i + u11i * x1r;
                }
            }
            #pragma unroll
            for (int w = 0; w < 4; ++w) {
                const int cb = 1 << (3 - w);
                const int tb = 1 << (3 - ((w + 1) & 3));
                #pragma unroll
                for (int i = 0; i < 16; ++i) {
                    if ((i & cb) && !(i & tb)) {
                        const int i1 = i | tb;
                        float tr = ar[i]; ar[i] = ar[i1]; ar[i1] = tr;
                        float ti = ai[i]; ai[i] = ai[i1]; ai[i1] = ti;
                    }
                }
            }
        }
        #pragma unroll
        for (int i = 0; i < 16; ++i) { Vr[i][tid] = ar[i]; Vi[i][tid] = ai[i]; }
    }
    __syncthreads();

    // ---- phase B: M_w[k,kp] (256 threads) ----
    {
        const int k = tid >> 4, kp = tid & 15;
        float m0 = 0.f, m1 = 0.f, m2 = 0.f, m3 = 0.f;
        #pragma unroll
        for (int i = 0; i < 16; ++i) {
            const float pr = Vr[i][k] * Vr[i][kp] + Vi[i][k] * Vi[i][kp];
            m0 += ((i >> 3) & 1) ? -pr : pr;
            m1 += ((i >> 2) & 1) ? -pr : pr;
            m2 += ((i >> 1) & 1) ? -pr : pr;
            m3 += ( i       & 1) ? -pr : pr;
        }
        sM[tid] = make_float4(m0, m1, m2, m3);
    }
    __syncthreads();

    // ---- phase C: G_j[m] over the 3^4 basis (81 threads) ----
    if (tid < 81) {
        const int mm[4] = { tid / 27, (tid / 9) % 3, (tid / 3) % 3, tid % 3 };
        float h0 = 0.f, h1 = 0.f, h2 = 0.f, h3 = 0.f;
        #pragma unroll
        for (int t16 = 0; t16 < 16; ++t16) {
            int k = 0, kp = 0;
            float sgn = 0.0625f;
            #pragma unroll
            for (int w = 0; w < 4; ++w) {
                const int b = (t16 >> (3 - w)) & 1;
                int kw, kpw;
                if (mm[w] == 2) { kw = b; kpw = 1 - b; }
                else            { kw = b; kpw = b; if (mm[w] == 1 && b) sgn = -sgn; }
                k  |= kw  << (3 - w);
                kp |= kpw << (3 - w);
            }
            const float4 mv = sM[k * 16 + kp];
            h0 += sgn * mv.x; h1 += sgn * mv.y; h2 += sgn * mv.z; h3 += sgn * mv.w;
        }
        #pragma unroll
        for (int j = 0; j < 4; ++j) {
            sC[tid * 4 + j] = W[j * 4 + 0] * h0 + W[j * 4 + 1] * h1 +
                              W[j * 4 + 2] * h2 + W[j * 4 + 3] * h3;
        }
    }
    __syncthreads();

    // ---- phase D: multilinear form, QB_S contiguous samples per thread ----
    const int g  = blockIdx.x * 256 + tid;
    const float sc = scale[0];
    const float b0 = bias[0], b1 = bias[1], b2 = bias[2], b3 = bias[3];

    float e01[QB_S][9], e23[QB_S][9];
    bool valid[QB_S];
    #pragma unroll
    for (int s = 0; s < QB_S; ++s) {
        const int idx = g * QB_S + s;
        valid[s] = (idx < Bn);
        const float4 zv = valid[s] ? reinterpret_cast<const float4*>(z)[idx]
                                   : make_float4(0.f, 0.f, 0.f, 0.f);
        const float zz[4] = { zv.x, zv.y, zv.z, zv.w };
        float c[4], sn[4];
        #pragma unroll
        for (int w = 0; w < 4; ++w) {
            const float x = zz[w];
            const float e = __expf(-2.0f * fabsf(x));
            float t = __fdividef(1.0f - e, 1.0f + e);
            t = copysignf(t, x);
            __sincosf(t * sc, &sn[w], &c[w]);
        }
        e01[s][0] = 1.0f;  e01[s][1] = c[1];          e01[s][2] = sn[1];
        e01[s][3] = c[0];  e01[s][4] = c[0] * c[1];   e01[s][5] = c[0] * sn[1];
        e01[s][6] = sn[0]; e01[s][7] = sn[0] * c[1];  e01[s][8] = sn[0] * sn[1];
        e23[s][0] = 1.0f;  e23[s][1] = c[3];          e23[s][2] = sn[3];
        e23[s][3] = c[2];  e23[s][4] = c[2] * c[3];   e23[s][5] = c[2] * sn[3];
        e23[s][6] = sn[2]; e23[s][7] = sn[2] * c[3];  e23[s][8] = sn[2] * sn[3];
    }

    float acc[QB_S][4];
    #pragma unroll
    for (int s = 0; s < QB_S; ++s) {
        acc[s][0] = b0; acc[s][1] = b1; acc[s][2] = b2; acc[s][3] = b3;
    }

    #pragma unroll
    for (int u = 0; u < 9; ++u) {
        float tj[QB_S][4];
        #pragma unroll
        for (int s = 0; s < QB_S; ++s)
            tj[s][0] = tj[s][1] = tj[s][2] = tj[s][3] = 0.0f;
        #pragma unroll
        for (int v = 0; v < 9; ++v) {
            const float4 cc = reinterpret_cast<const float4*>(sC)[u * 9 + v];
            #pragma unroll
            for (int s = 0; s < QB_S; ++s) {
                const float ev = e23[s][v];
                tj[s][0] = fmaf(cc.x, ev, tj[s][0]);
                tj[s][1] = fmaf(cc.y, ev, tj[s][1]);
                tj[s][2] = fmaf(cc.z, ev, tj[s][2]);
                tj[s][3] = fmaf(cc.w, ev, tj[s][3]);
            }
        }
        #pragma unroll
        for (int s = 0; s < QB_S; ++s) {
            const float eu = e01[s][u];
            acc[s][0] = fmaf(eu, tj[s][0], acc[s][0]);
            acc[s][1] = fmaf(eu, tj[s][1], acc[s][1]);
            acc[s][2] = fmaf(eu, tj[s][2], acc[s][2]);
            acc[s][3] = fmaf(eu, tj[s][3], acc[s][3]);
        }
    }

    #pragma unroll
    for (int s = 0; s < QB_S; ++s) {
        const int idx = g * QB_S + s;
        if (valid[s])
            reinterpret_cast<float4*>(out)[idx] =
                make_float4(acc[s][0], acc[s][1], acc[s][2], acc[s][3]);
    }
}

extern "C" void kernel_launch(void* const* d_in, const int* in_sizes, int n_in,
                              void* d_out, int out_size, void* d_ws, size_t ws_size,
                              hipStream_t stream) {
    const float* z  = (const float*)d_in[0];   // (B,4)
    const float* sc = (const float*)d_in[1];   // scalar
    const float* qw = (const float*)d_in[2];   // (2,4,3)
    const float* W  = (const float*)d_in[3];   // (4,4)
    const float* bb = (const float*)d_in[4];   // (4,)
    float* out = (float*)d_out;

    const int Bn = in_sizes[0] / 4;
    const int threads_total = (Bn + QB_S - 1) / QB_S;
    const int blocks = (threads_total + 255) / 256;

    hipLaunchKernelGGL(qb_fused, dim3(blocks), dim3(256), 0, stream,
                       z, sc, qw, W, bb, out, Bn);
}

// Round 7
// 25.471 us; speedup vs baseline: 8.1580x; 1.3558x over previous
//
#include <hip/hip_runtime.h>
#include <hip/hip_bf16.h>
#include <math.h>

// QuantumBottle, fully fused single kernel.
// out_j = b_j + sum_{m in {1,cos,sin}^4} G_j[m] * prod_w u_w[m_w],
// u_w = (1, cos(theta_w), sin(theta_w)), theta_w = tanh(z_w)*scale.
// Each block redundantly builds the 81x4 coefficient table C in LDS,
// then evaluates the multilinear form for QB_S samples per thread.
//
// Round-7 lesson stack:
//  - R4/R5 counters prove every prior build SPILLED (VGPR 256 + 56 MB
//    scratch fetch; forced VGPR 64 -> 336 MB scratch writes).
//  - Root cause: fully-unrolled 81-term loop lets the scheduler hoist all
//    81 ds_read_b128 (324 VGPRs worth) -> demand > 256 -> spill.
//  - Fix: keep full unroll (compile-time indices -> registers) but fence
//    scheduling per u-block with asm volatile memory clobbers.

#define QB_S 4   // samples per thread (contiguous)

__global__ void __launch_bounds__(256) qb_fused(
    const float* __restrict__ z, const float* __restrict__ scale,
    const float* __restrict__ qw, const float* __restrict__ W,
    const float* __restrict__ bias, float* __restrict__ out, int Bn)
{
    __shared__ float sTrig[8][6];
    __shared__ float Vr[16][16], Vi[16][16];
    __shared__ __align__(16) float4 sM[256];
    __shared__ __align__(16) float sC[81 * 4];

    const int tid = threadIdx.x;

    // ---- phase A1: trig table (24 threads, 1 sincos each) ----
    if (tid < 24) {
        const int g = tid / 3, which = tid % 3;
        const float phi = qw[g * 3 + 0], th = qw[g * 3 + 1], om = qw[g * 3 + 2];
        const float ang = (which == 0) ? 0.5f * th
                        : (which == 1) ? 0.5f * (phi + om)
                                       : 0.5f * (phi - om);
        sTrig[g][2 * which + 0] = cosf(ang);
        sTrig[g][2 * which + 1] = sinf(ang);
    }
    __syncthreads();

    // ---- phase A2: simulate circuit columns (16 threads) ----
    // All loops explicitly unrolled so ar/ai indices are compile-time
    // constants -> register file, never scratch (rule #20).
    if (tid < 16) {
        float ar[16], ai[16];
        #pragma unroll
        for (int i = 0; i < 16; ++i) { ar[i] = (i == tid) ? 1.0f : 0.0f; ai[i] = 0.0f; }

        #pragma unroll
        for (int l = 0; l < 2; ++l) {
            #pragma unroll
            for (int w = 0; w < 4; ++w) {
                const int g = l * 4 + w;
                const float ct  = sTrig[g][0], st  = sTrig[g][1];
                const float epr = sTrig[g][2], epi = -sTrig[g][3];
                const float emr = sTrig[g][4], emi = -sTrig[g][5];
                const float u00r =  epr * ct, u00i =  epi * ct;
                const float u01r = -emr * st, u01i =  emi * st;
                const float u10r =  emr * st, u10i =  emi * st;
                const float u11r =  epr * ct, u11i = -epi * ct;
                const int bit = 1 << (3 - w);
                #pragma unroll
                for (int i = 0; i < 16; ++i) {
                    if (i & bit) continue;
                    const int i1 = i | bit;
                    const float x0r = ar[i],  x0i = ai[i];
                    const float x1r = ar[i1], x1i = ai[i1];
                    ar[i]  = u00r * x0r - u00i * x0i + u01r * x1r - u01i * x1i;
                    ai[i]  = u00r * x0i + u00i * x0r + u01r * x1i + u01i * x1r;
                    ar[i1] = u10r * x0r - u10i * x0i + u11r * x1r - u11i * x1i;
                    ai[i1] = u10r * x0i + u10i * x0r + u11r * x1i + u11i * x1r;
                }
            }
            #pragma unroll
            for (int w = 0; w < 4; ++w) {
                const int cb = 1 << (3 - w);
                const int tb = 1 << (3 - ((w + 1) & 3));
                #pragma unroll
                for (int i = 0; i < 16; ++i) {
                    if ((i & cb) && !(i & tb)) {
                        const int i1 = i | tb;
                        float tr = ar[i]; ar[i] = ar[i1]; ar[i1] = tr;
                        float ti = ai[i]; ai[i] = ai[i1]; ai[i1] = ti;
                    }
                }
            }
        }
        #pragma unroll
        for (int i = 0; i < 16; ++i) { Vr[i][tid] = ar[i]; Vi[i][tid] = ai[i]; }
    }
    __syncthreads();

    // ---- phase B: M_w[k,kp] (256 threads) ----
    {
        const int k = tid >> 4, kp = tid & 15;
        float m0 = 0.f, m1 = 0.f, m2 = 0.f, m3 = 0.f;
        #pragma unroll
        for (int i = 0; i < 16; ++i) {
            const float pr = Vr[i][k] * Vr[i][kp] + Vi[i][k] * Vi[i][kp];
            m0 += ((i >> 3) & 1) ? -pr : pr;
            m1 += ((i >> 2) & 1) ? -pr : pr;
            m2 += ((i >> 1) & 1) ? -pr : pr;
            m3 += ( i       & 1) ? -pr : pr;
        }
        sM[tid] = make_float4(m0, m1, m2, m3);
    }
    __syncthreads();

    // ---- phase C: G_j[m] over the 3^4 basis (81 threads) ----
    if (tid < 81) {
        const int mm[4] = { tid / 27, (tid / 9) % 3, (tid / 3) % 3, tid % 3 };
        float h0 = 0.f, h1 = 0.f, h2 = 0.f, h3 = 0.f;
        #pragma unroll
        for (int t16 = 0; t16 < 16; ++t16) {
            int k = 0, kp = 0;
            float sgn = 0.0625f;
            #pragma unroll
            for (int w = 0; w < 4; ++w) {
                const int b = (t16 >> (3 - w)) & 1;
                int kw, kpw;
                if (mm[w] == 2) { kw = b; kpw = 1 - b; }
                else            { kw = b; kpw = b; if (mm[w] == 1 && b) sgn = -sgn; }
                k  |= kw  << (3 - w);
                kp |= kpw << (3 - w);
            }
            const float4 mv = sM[k * 16 + kp];
            h0 += sgn * mv.x; h1 += sgn * mv.y; h2 += sgn * mv.z; h3 += sgn * mv.w;
        }
        #pragma unroll
        for (int j = 0; j < 4; ++j) {
            sC[tid * 4 + j] = W[j * 4 + 0] * h0 + W[j * 4 + 1] * h1 +
                              W[j * 4 + 2] * h2 + W[j * 4 + 3] * h3;
        }
    }
    __syncthreads();

    // ---- phase D: multilinear form, QB_S contiguous samples per thread ----
    const int g  = blockIdx.x * 256 + tid;
    const float sc = scale[0];
    const float b0 = bias[0], b1 = bias[1], b2 = bias[2], b3 = bias[3];

    float e01[QB_S][9], e23[QB_S][9];
    bool valid[QB_S];
    #pragma unroll
    for (int s = 0; s < QB_S; ++s) {
        const int idx = g * QB_S + s;
        valid[s] = (idx < Bn);
        const float4 zv = valid[s] ? reinterpret_cast<const float4*>(z)[idx]
                                   : make_float4(0.f, 0.f, 0.f, 0.f);
        const float zz[4] = { zv.x, zv.y, zv.z, zv.w };
        float c[4], sn[4];
        #pragma unroll
        for (int w = 0; w < 4; ++w) {
            const float x = zz[w];
            const float e = __expf(-2.0f * fabsf(x));
            float t = __fdividef(1.0f - e, 1.0f + e);
            t = copysignf(t, x);
            __sincosf(t * sc, &sn[w], &c[w]);
        }
        e01[s][0] = 1.0f;  e01[s][1] = c[1];          e01[s][2] = sn[1];
        e01[s][3] = c[0];  e01[s][4] = c[0] * c[1];   e01[s][5] = c[0] * sn[1];
        e01[s][6] = sn[0]; e01[s][7] = sn[0] * c[1];  e01[s][8] = sn[0] * sn[1];
        e23[s][0] = 1.0f;  e23[s][1] = c[3];          e23[s][2] = sn[3];
        e23[s][3] = c[2];  e23[s][4] = c[2] * c[3];   e23[s][5] = c[2] * sn[3];
        e23[s][6] = sn[2]; e23[s][7] = sn[2] * c[3];  e23[s][8] = sn[2] * sn[3];
    }

    float acc[QB_S][4];
    #pragma unroll
    for (int s = 0; s < QB_S; ++s) {
        acc[s][0] = b0; acc[s][1] = b1; acc[s][2] = b2; acc[s][3] = b3;
    }

    #pragma unroll
    for (int u = 0; u < 9; ++u) {
        float tj[QB_S][4];
        #pragma unroll
        for (int s = 0; s < QB_S; ++s)
            tj[s][0] = tj[s][1] = tj[s][2] = tj[s][3] = 0.0f;
        #pragma unroll
        for (int v = 0; v < 9; ++v) {
            const float4 cc = reinterpret_cast<const float4*>(sC)[u * 9 + v];
            #pragma unroll
            for (int s = 0; s < QB_S; ++s) {
                const float ev = e23[s][v];
                tj[s][0] = fmaf(cc.x, ev, tj[s][0]);
                tj[s][1] = fmaf(cc.y, ev, tj[s][1]);
                tj[s][2] = fmaf(cc.z, ev, tj[s][2]);
                tj[s][3] = fmaf(cc.w, ev, tj[s][3]);
            }
        }
        #pragma unroll
        for (int s = 0; s < QB_S; ++s) {
            const float eu = e01[s][u];
            acc[s][0] = fmaf(eu, tj[s][0], acc[s][0]);
            acc[s][1] = fmaf(eu, tj[s][1], acc[s][1]);
            acc[s][2] = fmaf(eu, tj[s][2], acc[s][2]);
            acc[s][3] = fmaf(eu, tj[s][3], acc[s][3]);
        }
        // Scheduling fence: forbid hoisting the next u-block's 9 LDS loads
        // above this point -> bounds peak VGPR pressure (anti-spill).
        asm volatile("" ::: "memory");
    }

    #pragma unroll
    for (int s = 0; s < QB_S; ++s) {
        const int idx = g * QB_S + s;
        if (valid[s])
            reinterpret_cast<float4*>(out)[idx] =
                make_float4(acc[s][0], acc[s][1], acc[s][2], acc[s][3]);
    }
}

extern "C" void kernel_launch(void* const* d_in, const int* in_sizes, int n_in,
                              void* d_out, int out_size, void* d_ws, size_t ws_size,
                              hipStream_t stream) {
    const float* z  = (const float*)d_in[0];   // (B,4)
    const float* sc = (const float*)d_in[1];   // scalar
    const float* qw = (const float*)d_in[2];   // (2,4,3)
    const float* W  = (const float*)d_in[3];   // (4,4)
    const float* bb = (const float*)d_in[4];   // (4,)
    float* out = (float*)d_out;

    const int Bn = in_sizes[0] / 4;
    const int threads_total = (Bn + QB_S - 1) / QB_S;
    const int blocks = (threads_total + 255) / 256;

    hipLaunchKernelGGL(qb_fused, dim3(blocks), dim3(256), 0, stream,
                       z, sc, qw, W, bb, out, Bn);
}

// Round 8
// 25.089 us; speedup vs baseline: 8.2821x; 1.0152x over previous
//
#include <hip/hip_runtime.h>
#include <hip/hip_bf16.h>
#include <math.h>

// QuantumBottle, fully fused single kernel.
// out_j = b_j + sum_{m in {1,cos,sin}^4} G_j[m] * prod_w u_w[m_w],
// u_w = (1, cos(theta_w), sin(theta_w)), theta_w = tanh(z_w)*scale.
// Each block redundantly builds the 81x4 coefficient table C in LDS,
// then evaluates the multilinear form for QB_S samples per thread.
//
// R8: minimize persistent VGPR pressure. e01 is NOT precomputed; only
// c0,s0,c1,s1 are kept and e01u is rebuilt per u-block (36 mults / 4
// samples). Peak live ~130 VGPR -> guaranteed spill-free. Per-u fence
// retained to stop cross-block LDS load hoisting.

#define QB_S 4   // samples per thread (contiguous)

__global__ void __launch_bounds__(256) qb_fused(
    const float* __restrict__ z, const float* __restrict__ scale,
    const float* __restrict__ qw, const float* __restrict__ W,
    const float* __restrict__ bias, float* __restrict__ out, int Bn)
{
    __shared__ float sTrig[8][6];
    __shared__ float Vr[16][16], Vi[16][16];
    __shared__ __align__(16) float4 sM[256];
    __shared__ __align__(16) float sC[81 * 4];

    const int tid = threadIdx.x;

    // ---- phase A1: trig table (24 threads, 1 sincos each) ----
    if (tid < 24) {
        const int g = tid / 3, which = tid % 3;
        const float phi = qw[g * 3 + 0], th = qw[g * 3 + 1], om = qw[g * 3 + 2];
        const float ang = (which == 0) ? 0.5f * th
                        : (which == 1) ? 0.5f * (phi + om)
                                       : 0.5f * (phi - om);
        sTrig[g][2 * which + 0] = cosf(ang);
        sTrig[g][2 * which + 1] = sinf(ang);
    }
    __syncthreads();

    // ---- phase A2: simulate circuit columns (16 threads) ----
    if (tid < 16) {
        float ar[16], ai[16];
        #pragma unroll
        for (int i = 0; i < 16; ++i) { ar[i] = (i == tid) ? 1.0f : 0.0f; ai[i] = 0.0f; }

        #pragma unroll
        for (int l = 0; l < 2; ++l) {
            #pragma unroll
            for (int w = 0; w < 4; ++w) {
                const int g = l * 4 + w;
                const float ct  = sTrig[g][0], st  = sTrig[g][1];
                const float epr = sTrig[g][2], epi = -sTrig[g][3];
                const float emr = sTrig[g][4], emi = -sTrig[g][5];
                const float u00r =  epr * ct, u00i =  epi * ct;
                const float u01r = -emr * st, u01i =  emi * st;
                const float u10r =  emr * st, u10i =  emi * st;
                const float u11r =  epr * ct, u11i = -epi * ct;
                const int bit = 1 << (3 - w);
                #pragma unroll
                for (int i = 0; i < 16; ++i) {
                    if (i & bit) continue;
                    const int i1 = i | bit;
                    const float x0r = ar[i],  x0i = ai[i];
                    const float x1r = ar[i1], x1i = ai[i1];
                    ar[i]  = u00r * x0r - u00i * x0i + u01r * x1r - u01i * x1i;
                    ai[i]  = u00r * x0i + u00i * x0r + u01r * x1i + u01i * x1r;
                    ar[i1] = u10r * x0r - u10i * x0i + u11r * x1r - u11i * x1i;
                    ai[i1] = u10r * x0i + u10i * x0r + u11r * x1i + u11i * x1r;
                }
            }
            #pragma unroll
            for (int w = 0; w < 4; ++w) {
                const int cb = 1 << (3 - w);
                const int tb = 1 << (3 - ((w + 1) & 3));
                #pragma unroll
                for (int i = 0; i < 16; ++i) {
                    if ((i & cb) && !(i & tb)) {
                        const int i1 = i | tb;
                        float tr = ar[i]; ar[i] = ar[i1]; ar[i1] = tr;
                        float ti = ai[i]; ai[i] = ai[i1]; ai[i1] = ti;
                    }
                }
            }
        }
        #pragma unroll
        for (int i = 0; i < 16; ++i) { Vr[i][tid] = ar[i]; Vi[i][tid] = ai[i]; }
    }
    __syncthreads();

    // ---- phase B: M_w[k,kp] (256 threads) ----
    {
        const int k = tid >> 4, kp = tid & 15;
        float m0 = 0.f, m1 = 0.f, m2 = 0.f, m3 = 0.f;
        #pragma unroll
        for (int i = 0; i < 16; ++i) {
            const float pr = Vr[i][k] * Vr[i][kp] + Vi[i][k] * Vi[i][kp];
            m0 += ((i >> 3) & 1) ? -pr : pr;
            m1 += ((i >> 2) & 1) ? -pr : pr;
            m2 += ((i >> 1) & 1) ? -pr : pr;
            m3 += ( i       & 1) ? -pr : pr;
        }
        sM[tid] = make_float4(m0, m1, m2, m3);
    }
    __syncthreads();

    // ---- phase C: G_j[m] over the 3^4 basis (81 threads) ----
    if (tid < 81) {
        const int mm[4] = { tid / 27, (tid / 9) % 3, (tid / 3) % 3, tid % 3 };
        float h0 = 0.f, h1 = 0.f, h2 = 0.f, h3 = 0.f;
        #pragma unroll
        for (int t16 = 0; t16 < 16; ++t16) {
            int k = 0, kp = 0;
            float sgn = 0.0625f;
            #pragma unroll
            for (int w = 0; w < 4; ++w) {
                const int b = (t16 >> (3 - w)) & 1;
                int kw, kpw;
                if (mm[w] == 2) { kw = b; kpw = 1 - b; }
                else            { kw = b; kpw = b; if (mm[w] == 1 && b) sgn = -sgn; }
                k  |= kw  << (3 - w);
                kp |= kpw << (3 - w);
            }
            const float4 mv = sM[k * 16 + kp];
            h0 += sgn * mv.x; h1 += sgn * mv.y; h2 += sgn * mv.z; h3 += sgn * mv.w;
        }
        #pragma unroll
        for (int j = 0; j < 4; ++j) {
            sC[tid * 4 + j] = W[j * 4 + 0] * h0 + W[j * 4 + 1] * h1 +
                              W[j * 4 + 2] * h2 + W[j * 4 + 3] * h3;
        }
    }
    __syncthreads();

    // ---- phase D: multilinear form, QB_S contiguous samples per thread ----
    const int g  = blockIdx.x * 256 + tid;
    const float sc = scale[0];
    const float b0 = bias[0], b1 = bias[1], b2 = bias[2], b3 = bias[3];

    // Persistent per-sample state: wire0/1 trig (16 regs) + e23 (36) + acc (16).
    float c0[QB_S], s0[QB_S], c1[QB_S], s1[QB_S];
    float e23[QB_S][9];
    float acc[QB_S][4];
    bool valid[QB_S];

    #pragma unroll
    for (int s = 0; s < QB_S; ++s) {
        const int idx = g * QB_S + s;
        valid[s] = (idx < Bn);
        const float4 zv = valid[s] ? reinterpret_cast<const float4*>(z)[idx]
                                   : make_float4(0.f, 0.f, 0.f, 0.f);
        const float zz[4] = { zv.x, zv.y, zv.z, zv.w };
        float c[4], sn[4];
        #pragma unroll
        for (int w = 0; w < 4; ++w) {
            const float x = zz[w];
            const float e = __expf(-2.0f * fabsf(x));
            float t = __fdividef(1.0f - e, 1.0f + e);
            t = copysignf(t, x);
            __sincosf(t * sc, &sn[w], &c[w]);
        }
        c0[s] = c[0]; s0[s] = sn[0]; c1[s] = c[1]; s1[s] = sn[1];
        e23[s][0] = 1.0f;  e23[s][1] = c[3];          e23[s][2] = sn[3];
        e23[s][3] = c[2];  e23[s][4] = c[2] * c[3];   e23[s][5] = c[2] * sn[3];
        e23[s][6] = sn[2]; e23[s][7] = sn[2] * c[3];  e23[s][8] = sn[2] * sn[3];
        acc[s][0] = b0; acc[s][1] = b1; acc[s][2] = b2; acc[s][3] = b3;
    }

    #pragma unroll
    for (int u = 0; u < 9; ++u) {
        // rebuild e01u from c0/s0/c1/s1 (u compile-time -> folds; u==0 row is 1.0)
        float e01u[QB_S];
        #pragma unroll
        for (int s = 0; s < QB_S; ++s) {
            const float fa = (u / 3 == 0) ? 1.0f : (u / 3 == 1 ? c0[s] : s0[s]);
            const float fb = (u % 3 == 0) ? 1.0f : (u % 3 == 1 ? c1[s] : s1[s]);
            e01u[s] = fa * fb;
        }
        float tj[QB_S][4];
        #pragma unroll
        for (int s = 0; s < QB_S; ++s)
            tj[s][0] = tj[s][1] = tj[s][2] = tj[s][3] = 0.0f;
        #pragma unroll
        for (int v = 0; v < 9; ++v) {
            const float4 cc = reinterpret_cast<const float4*>(sC)[u * 9 + v];
            #pragma unroll
            for (int s = 0; s < QB_S; ++s) {
                const float ev = e23[s][v];
                tj[s][0] = fmaf(cc.x, ev, tj[s][0]);
                tj[s][1] = fmaf(cc.y, ev, tj[s][1]);
                tj[s][2] = fmaf(cc.z, ev, tj[s][2]);
                tj[s][3] = fmaf(cc.w, ev, tj[s][3]);
            }
        }
        #pragma unroll
        for (int s = 0; s < QB_S; ++s) {
            acc[s][0] = fmaf(e01u[s], tj[s][0], acc[s][0]);
            acc[s][1] = fmaf(e01u[s], tj[s][1], acc[s][1]);
            acc[s][2] = fmaf(e01u[s], tj[s][2], acc[s][2]);
            acc[s][3] = fmaf(e01u[s], tj[s][3], acc[s][3]);
        }
        // Fence: forbid hoisting the next u-block's LDS loads above here
        // (bounds peak VGPR pressure; R4/R5 proved spill is catastrophic).
        asm volatile("" ::: "memory");
    }

    #pragma unroll
    for (int s = 0; s < QB_S; ++s) {
        const int idx = g * QB_S + s;
        if (valid[s])
            reinterpret_cast<float4*>(out)[idx] =
                make_float4(acc[s][0], acc[s][1], acc[s][2], acc[s][3]);
    }
}

extern "C" void kernel_launch(void* const* d_in, const int* in_sizes, int n_in,
                              void* d_out, int out_size, void* d_ws, size_t ws_size,
                              hipStream_t stream) {
    const float* z  = (const float*)d_in[0];   // (B,4)
    const float* sc = (const float*)d_in[1];   // scalar
    const float* qw = (const float*)d_in[2];   // (2,4,3)
    const float* W  = (const float*)d_in[3];   // (4,4)
    const float* bb = (const float*)d_in[4];   // (4,)
    float* out = (float*)d_out;

    const int Bn = in_sizes[0] / 4;
    const int threads_total = (Bn + QB_S - 1) / QB_S;
    const int blocks = (threads_total + 255) / 256;

    hipLaunchKernelGGL(qb_fused, dim3(blocks), dim3(256), 0, stream,
                       z, sc, qw, W, bb, out, Bn);
}

// Round 9
// 22.242 us; speedup vs baseline: 9.3425x; 1.1280x over previous
//
#include <hip/hip_runtime.h>
#include <hip/hip_bf16.h>
#include <math.h>

// QuantumBottle, fully fused single kernel, parallel setup.
// out_j = b_j + sum_{m in {1,cos,sin}^4} G_j[m] * prod_w u_w[m_w],
// u_w = (1, cos(theta_w), sin(theta_w)), theta_w = tanh(z_w)*scale.
//
// R9: setup phases parallelized across all 256 threads.
//  - Layer unitary built as tensor product: entry[i][k] = prod_w U_w[i_w][k_w]
//    (3 complex mults per entry, 256 threads -> 1 instr-burst).
//  - CNOT ring folded in as a FREE row permutation sigma
//    (b1^=b0; b2^=b1; b3^=b2; b0^=b3 -- sequential ring on wire bits).
//  - Layer 2 applied as a 256-thread 16x16 complex matmul from LDS.
//  Replaces the old 1-wave, ~1500-instruction serial simulation (which was
//  ~35% of total kernel cycles while 3 of 4 waves idled at the barrier).
// Phase D identical to R8 (proven perf-identical, low VGPR pressure).

#define QB_S 4   // samples per thread (contiguous)

__device__ __forceinline__ float2 qb_cmul(float2 a, float2 b) {
    return make_float2(a.x * b.x - a.y * b.y, a.x * b.y + a.y * b.x);
}

__global__ void __launch_bounds__(256) qb_fused(
    const float* __restrict__ z, const float* __restrict__ scale,
    const float* __restrict__ qw, const float* __restrict__ W,
    const float* __restrict__ bias, float* __restrict__ out, int Bn)
{
    __shared__ float sTrig[8][6];          // per gate: ct, st, cos hp, sin hp, cos hm, sin hm
    __shared__ float2 sU[2][4][2][2];      // per layer/wire 2x2 Rot entries
    __shared__ float2 sV1[16][16];         // after layer 1 (perm applied)
    __shared__ float2 sU2[16][16];         // layer-2 tensor (no perm)
    __shared__ float Vr[16][16], Vi[16][16];  // final circuit unitary V
    __shared__ __align__(16) float4 sM[256];
    __shared__ __align__(16) float sC[81 * 4];

    const int tid = threadIdx.x;

    // ---- A1: trig table (24 threads, 1 fast sincos each) ----
    if (tid < 24) {
        const int g = tid / 3, which = tid % 3;
        const float phi = qw[g * 3 + 0], th = qw[g * 3 + 1], om = qw[g * 3 + 2];
        const float ang = (which == 0) ? 0.5f * th
                        : (which == 1) ? 0.5f * (phi + om)
                                       : 0.5f * (phi - om);
        float sn, cs;
        __sincosf(ang, &sn, &cs);
        sTrig[g][2 * which + 0] = cs;
        sTrig[g][2 * which + 1] = sn;
    }
    __syncthreads();

    // ---- A2a: 2x2 Rot gate entries (32 threads) ----
    // U = [[ep*ct, -conj(em)*st], [em*st, conj(ep)*ct]],
    // ep = (cos hp, -sin hp), em = (cos hm, -sin hm).
    if (tid < 32) {
        const int l = tid >> 4, w = (tid >> 2) & 3, r = (tid >> 1) & 1, c = tid & 1;
        const int g = l * 4 + w;
        const float ct  = sTrig[g][0], st  = sTrig[g][1];
        const float epr = sTrig[g][2], epi = -sTrig[g][3];
        const float emr = sTrig[g][4], emi = -sTrig[g][5];
        float re, im;
        if (r == 0 && c == 0)      { re =  epr * ct; im =  epi * ct; }
        else if (r == 0)           { re = -emr * st; im =  emi * st; }
        else if (c == 0)           { re =  emr * st; im =  emi * st; }
        else                       { re =  epr * ct; im = -epi * ct; }
        sU[l][w][r][c] = make_float2(re, im);
    }
    __syncthreads();

    // ---- A2b: tensor-product entries for both layers (256 threads) ----
    const int vi = tid >> 4, vk = tid & 15;
    const int i0 = (vi >> 3) & 1, i1 = (vi >> 2) & 1, i2 = (vi >> 1) & 1, i3 = vi & 1;
    const int k0 = (vk >> 3) & 1, k1 = (vk >> 2) & 1, k2 = (vk >> 1) & 1, k3 = vk & 1;
    // CNOT-ring permutation sigma of physical index vi
    int b0 = i0, b1 = i1, b2 = i2, b3 = i3;
    b1 ^= b0; b2 ^= b1; b3 ^= b2; b0 ^= b3;
    const int sig = (b0 << 3) | (b1 << 2) | (b2 << 1) | b3;
    {
        const float2 e1 = qb_cmul(qb_cmul(sU[0][0][i0][k0], sU[0][1][i1][k1]),
                                  qb_cmul(sU[0][2][i2][k2], sU[0][3][i3][k3]));
        const float2 e2 = qb_cmul(qb_cmul(sU[1][0][i0][k0], sU[1][1][i1][k1]),
                                  qb_cmul(sU[1][2][i2][k2], sU[1][3][i3][k3]));
        sV1[sig][vk] = e1;   // V1 = P * U1 (input is identity)
        sU2[vi][vk]  = e2;   // layer-2 tensor, perm applied at final write
    }
    __syncthreads();

    // ---- A2c: V = P * U2 * V1 via 16x16 complex matmul (256 threads) ----
    {
        float accr = 0.f, acci = 0.f;
        #pragma unroll
        for (int m = 0; m < 16; ++m) {
            const float2 u = sU2[vi][m];
            const float2 v = sV1[m][vk];
            accr += u.x * v.x - u.y * v.y;
            acci += u.x * v.y + u.y * v.x;
        }
        Vr[sig][vk] = accr;
        Vi[sig][vk] = acci;
    }
    __syncthreads();

    // ---- B: M_w[k,kp] = sum_i (+-)_w Re(conj(V[i,k]) V[i,kp]) (256 threads) ----
    {
        const int k = tid >> 4, kp = tid & 15;
        float m0 = 0.f, m1 = 0.f, m2 = 0.f, m3 = 0.f;
        #pragma unroll
        for (int i = 0; i < 16; ++i) {
            const float pr = Vr[i][k] * Vr[i][kp] + Vi[i][k] * Vi[i][kp];
            m0 += ((i >> 3) & 1) ? -pr : pr;
            m1 += ((i >> 2) & 1) ? -pr : pr;
            m2 += ((i >> 1) & 1) ? -pr : pr;
            m3 += ( i       & 1) ? -pr : pr;
        }
        sM[tid] = make_float4(m0, m1, m2, m3);
    }
    __syncthreads();

    // ---- C: G_j[m] over the 3^4 double-angle basis (81 threads) ----
    if (tid < 81) {
        const int mm[4] = { tid / 27, (tid / 9) % 3, (tid / 3) % 3, tid % 3 };
        float h0 = 0.f, h1 = 0.f, h2 = 0.f, h3 = 0.f;
        #pragma unroll
        for (int t16 = 0; t16 < 16; ++t16) {
            int k = 0, kp = 0;
            float sgn = 0.0625f;
            #pragma unroll
            for (int w = 0; w < 4; ++w) {
                const int b = (t16 >> (3 - w)) & 1;
                int kw, kpw;
                if (mm[w] == 2) { kw = b; kpw = 1 - b; }
                else            { kw = b; kpw = b; if (mm[w] == 1 && b) sgn = -sgn; }
                k  |= kw  << (3 - w);
                kp |= kpw << (3 - w);
            }
            const float4 mv = sM[k * 16 + kp];
            h0 += sgn * mv.x; h1 += sgn * mv.y; h2 += sgn * mv.z; h3 += sgn * mv.w;
        }
        #pragma unroll
        for (int j = 0; j < 4; ++j) {
            sC[tid * 4 + j] = W[j * 4 + 0] * h0 + W[j * 4 + 1] * h1 +
                              W[j * 4 + 2] * h2 + W[j * 4 + 3] * h3;
        }
    }
    __syncthreads();

    // ---- D: multilinear form, QB_S contiguous samples per thread (as R8) ----
    const int g  = blockIdx.x * 256 + tid;
    const float sc = scale[0];
    const float b0_ = bias[0], b1_ = bias[1], b2_ = bias[2], b3_ = bias[3];

    float c0[QB_S], s0[QB_S], c1[QB_S], s1[QB_S];
    float e23[QB_S][9];
    float acc[QB_S][4];
    bool valid[QB_S];

    #pragma unroll
    for (int s = 0; s < QB_S; ++s) {
        const int idx = g * QB_S + s;
        valid[s] = (idx < Bn);
        const float4 zv = valid[s] ? reinterpret_cast<const float4*>(z)[idx]
                                   : make_float4(0.f, 0.f, 0.f, 0.f);
        const float zz[4] = { zv.x, zv.y, zv.z, zv.w };
        float c[4], sn[4];
        #pragma unroll
        for (int w = 0; w < 4; ++w) {
            const float x = zz[w];
            const float e = __expf(-2.0f * fabsf(x));
            float t = __fdividef(1.0f - e, 1.0f + e);
            t = copysignf(t, x);
            __sincosf(t * sc, &sn[w], &c[w]);
        }
        c0[s] = c[0]; s0[s] = sn[0]; c1[s] = c[1]; s1[s] = sn[1];
        e23[s][0] = 1.0f;  e23[s][1] = c[3];          e23[s][2] = sn[3];
        e23[s][3] = c[2];  e23[s][4] = c[2] * c[3];   e23[s][5] = c[2] * sn[3];
        e23[s][6] = sn[2]; e23[s][7] = sn[2] * c[3];  e23[s][8] = sn[2] * sn[3];
        acc[s][0] = b0_; acc[s][1] = b1_; acc[s][2] = b2_; acc[s][3] = b3_;
    }

    #pragma unroll
    for (int u = 0; u < 9; ++u) {
        float e01u[QB_S];
        #pragma unroll
        for (int s = 0; s < QB_S; ++s) {
            const float fa = (u / 3 == 0) ? 1.0f : (u / 3 == 1 ? c0[s] : s0[s]);
            const float fb = (u % 3 == 0) ? 1.0f : (u % 3 == 1 ? c1[s] : s1[s]);
            e01u[s] = fa * fb;
        }
        float tj[QB_S][4];
        #pragma unroll
        for (int s = 0; s < QB_S; ++s)
            tj[s][0] = tj[s][1] = tj[s][2] = tj[s][3] = 0.0f;
        #pragma unroll
        for (int v = 0; v < 9; ++v) {
            const float4 cc = reinterpret_cast<const float4*>(sC)[u * 9 + v];
            #pragma unroll
            for (int s = 0; s < QB_S; ++s) {
                const float ev = e23[s][v];
                tj[s][0] = fmaf(cc.x, ev, tj[s][0]);
                tj[s][1] = fmaf(cc.y, ev, tj[s][1]);
                tj[s][2] = fmaf(cc.z, ev, tj[s][2]);
                tj[s][3] = fmaf(cc.w, ev, tj[s][3]);
            }
        }
        #pragma unroll
        for (int s = 0; s < QB_S; ++s) {
            acc[s][0] = fmaf(e01u[s], tj[s][0], acc[s][0]);
            acc[s][1] = fmaf(e01u[s], tj[s][1], acc[s][1]);
            acc[s][2] = fmaf(e01u[s], tj[s][2], acc[s][2]);
            acc[s][3] = fmaf(e01u[s], tj[s][3], acc[s][3]);
        }
        asm volatile("" ::: "memory");   // bound peak VGPR pressure (anti-spill)
    }

    #pragma unroll
    for (int s = 0; s < QB_S; ++s) {
        const int idx = g * QB_S + s;
        if (valid[s])
            reinterpret_cast<float4*>(out)[idx] =
                make_float4(acc[s][0], acc[s][1], acc[s][2], acc[s][3]);
    }
}

extern "C" void kernel_launch(void* const* d_in, const int* in_sizes, int n_in,
                              void* d_out, int out_size, void* d_ws, size_t ws_size,
                              hipStream_t stream) {
    const float* z  = (const float*)d_in[0];   // (B,4)
    const float* sc = (const float*)d_in[1];   // scalar
    const float* qw = (const float*)d_in[2];   // (2,4,3)
    const float* W  = (const float*)d_in[3];   // (4,4)
    const float* bb = (const float*)d_in[4];   // (4,)
    float* out = (float*)d_out;

    const int Bn = in_sizes[0] / 4;
    const int threads_total = (Bn + QB_S - 1) / QB_S;
    const int blocks = (threads_total + 255) / 256;

    hipLaunchKernelGGL(qb_fused, dim3(blocks), dim3(256), 0, stream,
                       z, sc, qw, W, bb, out, Bn);
}